// Round 2
// baseline (1629.422 us; speedup 1.0000x reference)
//
#include <hip/hip_runtime.h>
#include <hip/hip_bf16.h>
#include <math.h>

// Problem constants (Encoder_16750372454478)
#define D_MODEL 1024
#define HEADS   16
#define DKV     64
#define LAYERS  4
#define BATCH   8
#define SEQ     1024
#define NTOK    (BATCH*SEQ)      // 8192
#define LN_N    (SEQ*D_MODEL)    // per-sample LN element count
#define EPSV    1e-5f

typedef __attribute__((ext_vector_type(8))) short short8;   // 8 bf16 (4 VGPRs)
typedef __attribute__((ext_vector_type(4))) float floatx4;

__device__ __forceinline__ float bf2f(ushort u) {
    union { uint i; float f; } v; v.i = ((uint)u) << 16; return v.f;
}
__device__ __forceinline__ ushort f2bf(float f) {
    union { float f; uint i; } v; v.f = f;
    uint r = (v.i + 0x7fffu + ((v.i >> 16) & 1u)) >> 16;   // round-nearest-even
    return (ushort)r;
}
// pack two f32 -> one u32 of 2 bf16 (low = a, high = b). T12 recipe (no builtin).
__device__ __forceinline__ uint cvtpk(float a, float b) {
    uint r;
    asm("v_cvt_pk_bf16_f32 %0, %1, %2" : "=v"(r) : "v"(a), "v"(b));
    return r;
}

// async global->LDS, 16 B per lane (LDS dest = wave-uniform base + lane*16).
__device__ __forceinline__ void gload16(const ushort* g, ushort* l) {
    __builtin_amdgcn_global_load_lds(
        (const __attribute__((address_space(1))) void*)g,
        (__attribute__((address_space(3))) void*)l, 16, 0, 0);
}

// ---------------------------------------------------------------------------
// GEMM core, 2-phase double-buffered (T3-minimum): C[128x128], BK=32,
// 4 waves (2x2), 64x64 each. Next K-tile's global_load_lds issued into buf^1
// BEFORE compute on buf[cur]; one barrier per K-step (compiler's implicit
// vmcnt(0)-before-s_barrier provides the drain). LDS [2][128][32] per operand.
// ---------------------------------------------------------------------------
#define TBUF (128*32)
__device__ __forceinline__ void gemm_core128(
    const ushort* __restrict__ A, const ushort* __restrict__ B,
    int lda, int ldb, int Kd,
    ushort* ldsA, ushort* ldsB, floatx4 (&acc)[4][4])
{
    const int tid  = threadIdx.x;
    const int lane = tid & 63;
    const int w    = tid >> 6;
    const int wm   = w >> 1, wn = w & 1;
    const int mn   = lane & 15, quad = lane >> 4;
    const int srow = tid >> 2;
    const int scol = (tid & 3) * 8;
    const ushort* ga = A + (size_t)srow * lda + scol;
    const ushort* gb = B + (size_t)srow * ldb + scol;
    ushort* la = ldsA + srow * 32 + scol;
    ushort* lb = ldsB + srow * 32 + scol;

    // prologue: stage tile 0 into buf 0
    gload16(ga, la);
    gload16(ga + (size_t)64 * lda, la + 64 * 32);
    gload16(gb, lb);
    gload16(gb + (size_t)64 * ldb, lb + 64 * 32);
    __syncthreads();

    int cur = 0;
    for (int k0 = 0; k0 < Kd; k0 += 32) {
        const int nxt = cur ^ 1;
        if (k0 + 32 < Kd) {     // issue next tile's loads; fly under MFMA
            gload16(ga + k0 + 32, la + nxt * TBUF);
            gload16(ga + (size_t)64 * lda + k0 + 32, la + nxt * TBUF + 64 * 32);
            gload16(gb + k0 + 32, lb + nxt * TBUF);
            gload16(gb + (size_t)64 * ldb + k0 + 32, lb + nxt * TBUF + 64 * 32);
        }
        const ushort* cA = ldsA + cur * TBUF;
        const ushort* cB = ldsB + cur * TBUF;
        short8 af[4], bfr[4];
#pragma unroll
        for (int i = 0; i < 4; i++)
            af[i] = *(const short8*)(cA + (wm * 64 + i * 16 + mn) * 32 + quad * 8);
#pragma unroll
        for (int j = 0; j < 4; j++)
            bfr[j] = *(const short8*)(cB + (wn * 64 + j * 16 + mn) * 32 + quad * 8);
#pragma unroll
        for (int i = 0; i < 4; i++)
#pragma unroll
            for (int j = 0; j < 4; j++)
                acc[i][j] = __builtin_amdgcn_mfma_f32_16x16x32_bf16(af[i], bfr[j], acc[i][j], 0, 0, 0);
        __syncthreads();   // implicit vmcnt(0): next tile landed; buf swap safe
        cur = nxt;
    }
}

// ---------------------------------------------------------------------------
// Generic GEMM: out = A[M,K] B[N,K]^T (+bias)(+relu)(+resid->stats)(fp32 out).
// XCD-chunked bijective swizzle, y-fastest within each XCD's x-octet:
// per XCD working set = 8 A-tiles (2MB) + all 8 weight tiles (2MB) ~= L2.
// ---------------------------------------------------------------------------
__global__ __launch_bounds__(256) void gemm_bt128(
    const ushort* __restrict__ A, const ushort* __restrict__ B,
    const float* __restrict__ bias, ushort* __restrict__ C,
    const ushort* __restrict__ resid, float* __restrict__ stats,
    float* __restrict__ outF, int relu)
{
    __shared__ ushort ldsA[2 * TBUF], ldsB[2 * TBUF];
    __shared__ float sred1[4], sred2[4];
    // swizzle: grid (64,8) = 512 blocks; xcd = lid&7 (HW round-robin axis)
    const int lid = blockIdx.y * 64 + blockIdx.x;
    const int xcd = lid & 7, idx = lid >> 3;          // idx in [0,64)
    const int bx = xcd * 8 + (idx >> 3);              // 8 x-tiles per XCD
    const int by = idx & 7;                           // y fastest
    floatx4 acc[4][4];
#pragma unroll
    for (int i = 0; i < 4; i++)
#pragma unroll
        for (int j = 0; j < 4; j++) acc[i][j] = (floatx4){0.f, 0.f, 0.f, 0.f};

    gemm_core128(A + (size_t)bx * 128 * D_MODEL,
                 B + (size_t)by * 128 * D_MODEL,
                 D_MODEL, D_MODEL, D_MODEL, ldsA, ldsB, acc);

    const int lane = threadIdx.x & 63, w = threadIdx.x >> 6;
    const int wm = w >> 1, wn = w & 1;
    const int mn = lane & 15, quad = lane >> 4;
    float ssum = 0.f, ssq = 0.f;
#pragma unroll
    for (int i = 0; i < 4; i++) {
#pragma unroll
        for (int j = 0; j < 4; j++) {
            int col = by * 128 + wn * 64 + j * 16 + mn;
            float bv = bias ? bias[col] : 0.f;
#pragma unroll
            for (int r = 0; r < 4; r++) {
                int row = bx * 128 + wm * 64 + i * 16 + quad * 4 + r;
                float v = acc[i][j][r] + bv;
                if (relu) v = fmaxf(v, 0.f);
                if (resid) {
                    v += bf2f(resid[(size_t)row * D_MODEL + col]);
                    ssum += v; ssq += v * v;
                }
                if (outF) outF[(size_t)row * D_MODEL + col] = v;
                else      C[(size_t)row * D_MODEL + col] = f2bf(v);
            }
        }
    }
    if (stats) {
        for (int o = 1; o < 64; o <<= 1) {
            ssum += __shfl_xor(ssum, o); ssq += __shfl_xor(ssq, o);
        }
        if (lane == 0) { sred1[w] = ssum; sred2[w] = ssq; }
        __syncthreads();
        if (threadIdx.x == 0) {
            int b = bx >> 3;
            atomicAdd(&stats[b * 32],      sred1[0] + sred1[1] + sred1[2] + sred1[3]);
            atomicAdd(&stats[b * 32 + 16], sred2[0] + sred2[1] + sred2[2] + sred2[3]);
        }
    }
}

// ---------------------------------------------------------------------------
// Fused Q/K/V projection: 1536 blocks. Swizzled: xcd = lid&7, within XCD
// 8 x-tiles with byy (0..23) fastest. which = byy>>3 (0=Q,1=K,2=V), nb=byy&7.
// V stored transposed per head into Vt with packed 8B stores (r -> 4
// consecutive t), replacing 64 scattered 2B stores per thread.
// ---------------------------------------------------------------------------
__global__ __launch_bounds__(256) void gemm_qkv(
    const ushort* __restrict__ X, const ushort* __restrict__ Wq,
    const ushort* __restrict__ Wk, const ushort* __restrict__ Wv,
    ushort* __restrict__ Q, ushort* __restrict__ K, ushort* __restrict__ Vt)
{
    __shared__ ushort ldsA[2 * TBUF], ldsB[2 * TBUF];
    const int lid = blockIdx.y * 64 + blockIdx.x;     // grid (64,24)
    const int xcd = lid & 7, idx = lid >> 3;          // idx in [0,192)
    const int bx = xcd * 8 + idx / 24;                // 8 x-tiles per XCD
    const int byy = idx % 24;                         // y fastest
    const int which = byy >> 3;
    const int nb = byy & 7;
    const ushort* B = (which == 0) ? Wq : (which == 1) ? Wk : Wv;
    floatx4 acc[4][4];
#pragma unroll
    for (int i = 0; i < 4; i++)
#pragma unroll
        for (int j = 0; j < 4; j++) acc[i][j] = (floatx4){0.f, 0.f, 0.f, 0.f};

    gemm_core128(X + (size_t)bx * 128 * D_MODEL,
                 B + (size_t)nb * 128 * D_MODEL,
                 D_MODEL, D_MODEL, D_MODEL, ldsA, ldsB, acc);

    const int lane = threadIdx.x & 63, w = threadIdx.x >> 6;
    const int wm = w >> 1, wn = w & 1;
    const int mn = lane & 15, quad = lane >> 4;
    if (which == 2) {
        // Vt[(b*H+h)*DKV+kk][t]: r = consecutive t -> pack 4 bf16 = 8B store
#pragma unroll
        for (int i = 0; i < 4; i++) {
#pragma unroll
            for (int j = 0; j < 4; j++) {
                int col = nb * 128 + wn * 64 + j * 16 + mn;
                int h = col >> 6, kk = col & 63;
                int row0 = bx * 128 + wm * 64 + i * 16 + quad * 4;
                int b = row0 >> 10, t0 = row0 & 1023;
                uint2 uu;
                uu.x = cvtpk(acc[i][j][0], acc[i][j][1]);
                uu.y = cvtpk(acc[i][j][2], acc[i][j][3]);
                *(uint2*)(Vt + (((size_t)(b * HEADS + h)) * DKV + kk) * SEQ + t0) = uu;
            }
        }
    } else {
        ushort* dst = (which == 0) ? Q : K;
#pragma unroll
        for (int i = 0; i < 4; i++) {
#pragma unroll
            for (int j = 0; j < 4; j++) {
                int col = nb * 128 + wn * 64 + j * 16 + mn;
#pragma unroll
                for (int r = 0; r < 4; r++) {
                    int row = bx * 128 + wm * 64 + i * 16 + quad * 4 + r;
                    dst[(size_t)row * D_MODEL + col] = f2bf(acc[i][j][r]);
                }
            }
        }
    }
}

// ---------------------------------------------------------------------------
// Flash attention, swapped-QK^T structure (T12-style, adapted to 16x16x32):
//   S^T = mfma(K_frag, Q_frag)  ->  lane (mn,quad) holds S[key=j*16+quad*4+r][q=mn]
//   => softmax row-sum is lane-local over (j,r) + 2 shuffles over quad.
//   P -> PV A-fragments via cvt_pk_bf16 pairs + ds_write_b64 into the DEAD lQ
//   buffer (Q frags hoisted to regs; each wave touches only its own 32 rows
//   => NO __syncthreads on the P path). 2 barriers/tile instead of 6.
// No-max online softmax (scores analytically bounded; Q pre-scaled 1/8).
// Async-stage split (T14): next K/V tile's global loads issued before compute,
// LDS write after the end-of-tile barrier. setprio(1) around MFMA clusters.
// LDS 53KB: Q/K stride 72, V stride 136 (all access patterns <=2-way, free).
// ---------------------------------------------------------------------------
#define SQK 72
#define SV  136
__global__ __launch_bounds__(256) void flash_attn(
    const ushort* __restrict__ Q, const ushort* __restrict__ K,
    const ushort* __restrict__ Vt, ushort* __restrict__ O)
{
    __shared__ ushort lQ[128 * SQK];   // Q tile, then per-wave P transfer buffer
    __shared__ ushort lK[128 * SQK];
    __shared__ ushort lV[64 * SV];
    const int tid = threadIdx.x, lane = tid & 63, w = tid >> 6;
    const int mn = lane & 15, quad = lane >> 4;
    const int pair = blockIdx.x;        // 0..127
    const int qt = blockIdx.y;          // 0..7
    const int b = pair >> 4, h = pair & 15;
    const ushort* Qb = Q + ((size_t)b * SEQ) * D_MODEL + h * DKV;
    const ushort* Kb = K + ((size_t)b * SEQ) * D_MODEL + h * DKV;
    const ushort* Vb = Vt + (size_t)pair * DKV * SEQ;

    // stage Q tile [128][64], pre-scaled by 1/8 (exact in bf16)
#pragma unroll
    for (int c = 0; c < 4; c++) {
        int idx = c * 256 + tid;
        int row = idx >> 3, col = (idx & 7) * 8;
        short8 qv = *(const short8*)(Qb + (size_t)(qt * 128 + row) * D_MODEL + col);
        short8 qs;
#pragma unroll
        for (int e = 0; e < 8; e++) qs[e] = (short)f2bf(bf2f((ushort)qv[e]) * 0.125f);
        *(short8*)(lQ + row * SQK + col) = qs;
    }
    // prologue: K/V tile 0 global->regs (write to LDS after Q-stage barrier)
    short8 kreg[4], vreg[4];
#pragma unroll
    for (int c = 0; c < 4; c++) {
        int idx = c * 256 + tid;
        int row = idx >> 3, col = (idx & 7) * 8;
        kreg[c] = *(const short8*)(Kb + (size_t)row * D_MODEL + col);
        int vr = idx >> 4, vc = (idx & 15) * 8;
        vreg[c] = *(const short8*)(Vb + (size_t)vr * SEQ + vc);
    }
    __syncthreads();

    // hoist Q B-fragments (constant across all K-tiles); lQ rows [w*32,w*32+32)
    // are wave-private from here on -> reusable as the P transfer buffer.
    short8 bq[2][2];
#pragma unroll
    for (int i = 0; i < 2; i++)
#pragma unroll
        for (int kk = 0; kk < 2; kk++)
            bq[i][kk] = *(const short8*)(lQ + (w * 32 + i * 16 + mn) * SQK + kk * 32 + quad * 8);

    // write K/V tile 0 to LDS
#pragma unroll
    for (int c = 0; c < 4; c++) {
        int idx = c * 256 + tid;
        int row = idx >> 3, col = (idx & 7) * 8;
        *(short8*)(lK + row * SQK + col) = kreg[c];
        int vr = idx >> 4, vc = (idx & 15) * 8;
        *(short8*)(lV + vr * SV + vc) = vreg[c];
    }
    __syncthreads();

    floatx4 acc_o[2][4];
    float lrow[2] = {0.f, 0.f};
#pragma unroll
    for (int i = 0; i < 2; i++)
#pragma unroll
        for (int jo = 0; jo < 4; jo++) acc_o[i][jo] = (floatx4){0.f, 0.f, 0.f, 0.f};

    for (int tk = 0; tk < 8; tk++) {
        // T14: issue next tile's global loads now; latency hides under compute
        if (tk < 7) {
#pragma unroll
            for (int c = 0; c < 4; c++) {
                int idx = c * 256 + tid;
                int row = idx >> 3, col = (idx & 7) * 8;
                kreg[c] = *(const short8*)(Kb + (size_t)((tk + 1) * 128 + row) * D_MODEL + col);
                int vr = idx >> 4, vc = (idx & 15) * 8;
                vreg[c] = *(const short8*)(Vb + (size_t)vr * SEQ + (tk + 1) * 128 + vc);
            }
        }

        // S^T = mfma(K, Q/8): s[i][j][r] = S[key=j*16+quad*4+r][q=w*32+i*16+mn]
        floatx4 s[2][8];
#pragma unroll
        for (int i = 0; i < 2; i++)
#pragma unroll
            for (int j = 0; j < 8; j++) s[i][j] = (floatx4){0.f, 0.f, 0.f, 0.f};
        __builtin_amdgcn_s_setprio(1);
#pragma unroll
        for (int kk = 0; kk < 2; kk++) {
#pragma unroll
            for (int j = 0; j < 8; j++) {
                short8 ak = *(const short8*)(lK + (j * 16 + mn) * SQK + kk * 32 + quad * 8);
                s[0][j] = __builtin_amdgcn_mfma_f32_16x16x32_bf16(ak, bq[0][kk], s[0][j], 0, 0, 0);
                s[1][j] = __builtin_amdgcn_mfma_f32_16x16x32_bf16(ak, bq[1][kk], s[1][j], 0, 0, 0);
            }
        }
        __builtin_amdgcn_s_setprio(0);

        // softmax numerator, no max shift; row (q=mn) sum is lane-local + 2 shfl
#pragma unroll
        for (int i = 0; i < 2; i++) {
            float ps = 0.f;
#pragma unroll
            for (int j = 0; j < 8; j++)
#pragma unroll
                for (int r = 0; r < 4; r++) {
                    float p = __expf(s[i][j][r]);
                    s[i][j][r] = p;
                    ps += p;
                }
            ps += __shfl_xor(ps, 16);
            ps += __shfl_xor(ps, 32);
            lrow[i] += ps;
        }

        // P transfer through wave-private lQ rows, two 64-key halves, no barriers.
        // Write: key j*16+quad*4+{0..3} of row q -> bytes (key&63)*2 of row q.
        // Read:  A-frag kk: row mn, bytes (kk&1)*64 + quad*16 (exact match).
#pragma unroll
        for (int hf = 0; hf < 2; hf++) {
#pragma unroll
            for (int i = 0; i < 2; i++)
#pragma unroll
                for (int jl = 0; jl < 4; jl++) {
                    int j = hf * 4 + jl;
                    uint2 uu;
                    uu.x = cvtpk(s[i][j][0], s[i][j][1]);
                    uu.y = cvtpk(s[i][j][2], s[i][j][3]);
                    *(uint2*)(lQ + (w * 32 + i * 16 + mn) * SQK + jl * 16 + quad * 4) = uu;
                }
            __builtin_amdgcn_s_setprio(1);
#pragma unroll
            for (int kkl = 0; kkl < 2; kkl++) {
                int kk = hf * 2 + kkl;
                short8 pa0 = *(const short8*)(lQ + (w * 32 + 0  + mn) * SQK + kkl * 32 + quad * 8);
                short8 pa1 = *(const short8*)(lQ + (w * 32 + 16 + mn) * SQK + kkl * 32 + quad * 8);
#pragma unroll
                for (int jo = 0; jo < 4; jo++) {
                    short8 bv = *(const short8*)(lV + (jo * 16 + mn) * SV + kk * 32 + quad * 8);
                    acc_o[0][jo] = __builtin_amdgcn_mfma_f32_16x16x32_bf16(pa0, bv, acc_o[0][jo], 0, 0, 0);
                    acc_o[1][jo] = __builtin_amdgcn_mfma_f32_16x16x32_bf16(pa1, bv, acc_o[1][jo], 0, 0, 0);
                }
            }
            __builtin_amdgcn_s_setprio(0);
        }

        __syncthreads();   // all waves done reading lK/lV
        if (tk < 7) {
#pragma unroll
            for (int c = 0; c < 4; c++) {
                int idx = c * 256 + tid;
                int row = idx >> 3, col = (idx & 7) * 8;
                *(short8*)(lK + row * SQK + col) = kreg[c];
                int vr = idx >> 4, vc = (idx & 15) * 8;
                *(short8*)(lV + vr * SV + vc) = vreg[c];
            }
            __syncthreads();
        }
    }

    // epilogue: O = acc_o / l. acc_o[i][jo][r] = O[q=w*32+i*16+quad*4+r][d=jo*16+mn];
    // row-sum for q-row t lives in lanes with mn==t -> fetch via shuffle.
#pragma unroll
    for (int i = 0; i < 2; i++)
#pragma unroll
        for (int r = 0; r < 4; r++) {
            float rs = __shfl(lrow[i], quad * 4 + r);
            float rinv = 1.f / rs;
            int row = qt * 128 + w * 32 + i * 16 + quad * 4 + r;
#pragma unroll
            for (int jo = 0; jo < 4; jo++)
                O[((size_t)b * SEQ + row) * D_MODEL + h * DKV + jo * 16 + mn] =
                    f2bf(acc_o[i][jo][r] * rinv);
        }
}

// ---------------------------------------------------------------------------
// fp32 -> bf16 bulk convert
__global__ __launch_bounds__(256) void cvt_f32_bf16(const float* __restrict__ src,
                                                    ushort* __restrict__ dst) {
    size_t base = ((size_t)blockIdx.x * 256 + threadIdx.x) * 8;
    float4 a = *(const float4*)(src + base);
    float4 b = *(const float4*)(src + base + 4);
    short8 o;
    o[0] = (short)f2bf(a.x); o[1] = (short)f2bf(a.y);
    o[2] = (short)f2bf(a.z); o[3] = (short)f2bf(a.w);
    o[4] = (short)f2bf(b.x); o[5] = (short)f2bf(b.y);
    o[6] = (short)f2bf(b.z); o[7] = (short)f2bf(b.w);
    *(short8*)(dst + base) = o;
}

// x = X + positional encoding (base 1000, per reference). fp32 in, bf16 out.
__global__ __launch_bounds__(256) void add_pos(const float* __restrict__ X,
                                               ushort* __restrict__ x) {
    size_t idx = (size_t)blockIdx.x * 256 + threadIdx.x;
    int d = (int)(idx & (D_MODEL - 1));
    int s = (int)((idx >> 10) & (SEQ - 1));
    float freq = powf(1000.f, (float)(2 * (d >> 1)) * (1.f / (float)D_MODEL));
    float ang = (float)s / freq;
    float pe = (d & 1) ? cosf(ang) : sinf(ang);
    x[idx] = f2bf(X[idx] + pe);
}

__global__ __launch_bounds__(256) void ln_apply(
    const ushort* __restrict__ S, ushort* __restrict__ Y,
    const float* __restrict__ stats)
{
    size_t base = ((size_t)blockIdx.x * 256 + threadIdx.x) * 8;
    int b = blockIdx.x >> 9;
    float mean = stats[b * 32] * (1.f / (float)LN_N);
    float var = stats[b * 32 + 16] * (1.f / (float)LN_N) - mean * mean;
    float r = rsqrtf(var + EPSV);
    short8 sv = *(const short8*)(S + base);
    short8 ov;
#pragma unroll
    for (int i = 0; i < 8; i++) ov[i] = (short)f2bf((bf2f((ushort)sv[i]) - mean) * r);
    *(short8*)(Y + base) = ov;
}

__global__ void zero_stats(float* stats) { stats[threadIdx.x] = 0.f; }  // 256 thr

// ---------------------------------------------------------------------------
extern "C" void kernel_launch(void* const* d_in, const int* in_sizes, int n_in,
                              void* d_out, int out_size, void* d_ws, size_t ws_size,
                              hipStream_t stream) {
    const float* X    = (const float*)d_in[0];
    const float* Wq   = (const float*)d_in[1];
    const float* Wk   = (const float*)d_in[2];
    const float* Wv   = (const float*)d_in[3];
    const float* W0   = (const float*)d_in[4];
    const float* Wr_w = (const float*)d_in[5];
    const float* Wr_b = (const float*)d_in[6];
    const float* Wf0w = (const float*)d_in[7];
    const float* Wf0b = (const float*)d_in[8];
    const float* Wf1w = (const float*)d_in[9];
    const float* Wf1b = (const float*)d_in[10];
    float* out = (float*)d_out;

    char* ws = (char*)d_ws;
    size_t off = 0;
    auto alloc = [&](size_t bytes) -> void* {
        void* p = ws + off; off += (bytes + 255) & ~(size_t)255; return p;
    };
    const size_t ACT = (size_t)NTOK * D_MODEL * sizeof(ushort);     // 16 MB
    const size_t WTE = (size_t)LAYERS * D_MODEL * D_MODEL;          // elements/weight tensor
    ushort* x  = (ushort*)alloc(ACT);
    ushort* bQ = (ushort*)alloc(ACT);
    ushort* bK = (ushort*)alloc(ACT);
    ushort* bV = (ushort*)alloc(ACT);   // Vt: [B][H][DK][SEQ]
    ushort* bO = (ushort*)alloc(ACT);
    ushort* wq  = (ushort*)alloc(WTE * 2);
    ushort* wk  = (ushort*)alloc(WTE * 2);
    ushort* wv  = (ushort*)alloc(WTE * 2);
    ushort* w0  = (ushort*)alloc(WTE * 2);
    ushort* wr  = (ushort*)alloc(WTE * 2);
    ushort* wf0 = (ushort*)alloc(WTE * 2);
    ushort* wf1 = (ushort*)alloc(WTE * 2);
    float* stats = (float*)alloc(256 * sizeof(float));

    const int EW_BLOCKS = (NTOK * D_MODEL) / (256 * 8);        // 4096
    const int CVT_BLOCKS = (int)(WTE / (256 * 8));             // 2048
    const dim3 GEMM_GRID(NTOK / 128, D_MODEL / 128);           // (64, 8)
    const dim3 QKV_GRID(NTOK / 128, 3 * D_MODEL / 128);        // (64, 24)
    const dim3 FLASH_GRID(BATCH * HEADS, SEQ / 128);           // (128, 8)

    cvt_f32_bf16<<<CVT_BLOCKS, 256, 0, stream>>>(Wq,   wq);
    cvt_f32_bf16<<<CVT_BLOCKS, 256, 0, stream>>>(Wk,   wk);
    cvt_f32_bf16<<<CVT_BLOCKS, 256, 0, stream>>>(Wv,   wv);
    cvt_f32_bf16<<<CVT_BLOCKS, 256, 0, stream>>>(W0,   w0);
    cvt_f32_bf16<<<CVT_BLOCKS, 256, 0, stream>>>(Wr_w, wr);
    cvt_f32_bf16<<<CVT_BLOCKS, 256, 0, stream>>>(Wf0w, wf0);
    cvt_f32_bf16<<<CVT_BLOCKS, 256, 0, stream>>>(Wf1w, wf1);

    add_pos<<<(NTOK * D_MODEL) / 256, 256, 0, stream>>>(X, x);

    for (int l = 0; l < LAYERS; l++) {
        const size_t WO = (size_t)l * D_MODEL * D_MODEL;
        const ushort* Wq_l  = wq  + WO;
        const ushort* Wk_l  = wk  + WO;
        const ushort* Wv_l  = wv  + WO;
        const ushort* W0_l  = w0  + WO;
        const ushort* Wr_l  = wr  + WO;
        const ushort* W0w_l = wf0 + WO;
        const ushort* W1w_l = wf1 + WO;
        const float* Wrb_l = Wr_b + (size_t)l * D_MODEL;
        const float* W0b_l = Wf0b + (size_t)l * D_MODEL;
        const float* W1b_l = Wf1b + (size_t)l * D_MODEL;

        // Q,K,V projections (fused)
        gemm_qkv<<<QKV_GRID, 256, 0, stream>>>(x, Wq_l, Wk_l, Wv_l, bQ, bK, bV);

        flash_attn<<<FLASH_GRID, 256, 0, stream>>>(bQ, bK, bV, bO);

        // s1 = x + O@W0^T -> bK, + LN stats (fused epilogue)
        zero_stats<<<1, 256, 0, stream>>>(stats);
        gemm_bt128<<<GEMM_GRID, 256, 0, stream>>>(bO, W0_l, nullptr, bK,
            x, stats, nullptr, 0);
        // y1 = LN(s1) -> bO
        ln_apply<<<EW_BLOCKS, 256, 0, stream>>>(bK, bO, stats);
        // r0 = y1 @ Wr^T + br -> bV
        gemm_bt128<<<GEMM_GRID, 256, 0, stream>>>(bO, Wr_l, Wrb_l, bV,
            nullptr, nullptr, nullptr, 0);
        // h0 = relu(r0 @ Wf0^T + b0) -> bQ
        gemm_bt128<<<GEMM_GRID, 256, 0, stream>>>(bV, W0w_l, W0b_l, bQ,
            nullptr, nullptr, nullptr, 1);
        // s2 = r0 + h0 @ Wf1^T + b1 -> bK, + LN stats (fused)
        zero_stats<<<1, 256, 0, stream>>>(stats);
        gemm_bt128<<<GEMM_GRID, 256, 0, stream>>>(bQ, W1w_l, W1b_l, bK,
            bV, stats, nullptr, 0);
        // y2 = LN(s2) -> bO
        ln_apply<<<EW_BLOCKS, 256, 0, stream>>>(bK, bO, stats);
        // x = y2 @ Wr^T + br -> x (last layer: write fp32 directly to d_out)
        gemm_bt128<<<GEMM_GRID, 256, 0, stream>>>(bO, Wr_l, Wrb_l, x,
            nullptr, nullptr, (l == LAYERS - 1) ? out : nullptr, 0);
    }
}

// Round 3
// 1501.394 us; speedup vs baseline: 1.0853x; 1.0853x over previous
//
#include <hip/hip_runtime.h>
#include <hip/hip_bf16.h>
#include <math.h>

// Problem constants (Encoder_16750372454478)
#define D_MODEL 1024
#define HEADS   16
#define DKV     64
#define LAYERS  4
#define BATCH   8
#define SEQ     1024
#define NTOK    (BATCH*SEQ)      // 8192
#define LN_N    (SEQ*D_MODEL)    // per-sample LN element count
#define EPSV    1e-5f

typedef __attribute__((ext_vector_type(8))) short short8;   // 8 bf16 (4 VGPRs)
typedef __attribute__((ext_vector_type(4))) float floatx4;

__device__ __forceinline__ float bf2f(ushort u) {
    union { uint i; float f; } v; v.i = ((uint)u) << 16; return v.f;
}
__device__ __forceinline__ ushort f2bf(float f) {
    union { float f; uint i; } v; v.f = f;
    uint r = (v.i + 0x7fffu + ((v.i >> 16) & 1u)) >> 16;   // round-nearest-even
    return (ushort)r;
}
// pack two f32 -> one u32 of 2 bf16 (low = a, high = b). T12 recipe (no builtin).
__device__ __forceinline__ uint cvtpk(float a, float b) {
    uint r;
    asm("v_cvt_pk_bf16_f32 %0, %1, %2" : "=v"(r) : "v"(a), "v"(b));
    return r;
}
// permlane swaps (gfx950): a/c both read+written.
// pl32: a'[32:63]=c[0:31], c'[0:31]=a[32:63].  pl16: a'[16:31]=c[0:15],
// c'[0:15]=a[16:31], a'[48:63]=c[32:47], c'[32:47]=a[48:63].
__device__ __forceinline__ void pl32(uint &a, uint &c) {
    asm volatile("v_permlane32_swap_b32 %0, %1" : "+v"(a), "+v"(c));
}
__device__ __forceinline__ void pl16(uint &a, uint &c) {
    asm volatile("v_permlane16_swap_b32 %0, %1" : "+v"(a), "+v"(c));
}

// async global->LDS, 16 B per lane (LDS dest = wave-uniform base + lane*16).
__device__ __forceinline__ void gload16(const ushort* g, ushort* l) {
    __builtin_amdgcn_global_load_lds(
        (const __attribute__((address_space(1))) void*)g,
        (__attribute__((address_space(3))) void*)l, 16, 0, 0);
}

// ---------------------------------------------------------------------------
// GEMM core, 2-phase double-buffered (T3-minimum): C[128x128], BK=32,
// 4 waves (2x2), 64x64 each. Next K-tile's global_load_lds issued into buf^1
// BEFORE compute on buf[cur]; one barrier per K-step. LDS [2][128][32]/operand.
// ---------------------------------------------------------------------------
#define TBUF (128*32)
__device__ __forceinline__ void gemm_core128(
    const ushort* __restrict__ A, const ushort* __restrict__ B,
    int lda, int ldb, int Kd,
    ushort* ldsA, ushort* ldsB, floatx4 (&acc)[4][4])
{
    const int tid  = threadIdx.x;
    const int lane = tid & 63;
    const int w    = tid >> 6;
    const int wm   = w >> 1, wn = w & 1;
    const int mn   = lane & 15, quad = lane >> 4;
    const int srow = tid >> 2;
    const int scol = (tid & 3) * 8;
    const ushort* ga = A + (size_t)srow * lda + scol;
    const ushort* gb = B + (size_t)srow * ldb + scol;
    ushort* la = ldsA + srow * 32 + scol;
    ushort* lb = ldsB + srow * 32 + scol;

    // prologue: stage tile 0 into buf 0
    gload16(ga, la);
    gload16(ga + (size_t)64 * lda, la + 64 * 32);
    gload16(gb, lb);
    gload16(gb + (size_t)64 * ldb, lb + 64 * 32);
    __syncthreads();

    int cur = 0;
    for (int k0 = 0; k0 < Kd; k0 += 32) {
        const int nxt = cur ^ 1;
        if (k0 + 32 < Kd) {     // issue next tile's loads; fly under MFMA
            gload16(ga + k0 + 32, la + nxt * TBUF);
            gload16(ga + (size_t)64 * lda + k0 + 32, la + nxt * TBUF + 64 * 32);
            gload16(gb + k0 + 32, lb + nxt * TBUF);
            gload16(gb + (size_t)64 * ldb + k0 + 32, lb + nxt * TBUF + 64 * 32);
        }
        const ushort* cA = ldsA + cur * TBUF;
        const ushort* cB = ldsB + cur * TBUF;
        short8 af[4], bfr[4];
#pragma unroll
        for (int i = 0; i < 4; i++)
            af[i] = *(const short8*)(cA + (wm * 64 + i * 16 + mn) * 32 + quad * 8);
#pragma unroll
        for (int j = 0; j < 4; j++)
            bfr[j] = *(const short8*)(cB + (wn * 64 + j * 16 + mn) * 32 + quad * 8);
#pragma unroll
        for (int i = 0; i < 4; i++)
#pragma unroll
            for (int j = 0; j < 4; j++)
                acc[i][j] = __builtin_amdgcn_mfma_f32_16x16x32_bf16(af[i], bfr[j], acc[i][j], 0, 0, 0);
        __syncthreads();   // implicit vmcnt(0): next tile landed; buf swap safe
        cur = nxt;
    }
}

// ---------------------------------------------------------------------------
// Generic GEMM: out = A[M,K] B[N,K]^T (+bias)(+relu)(+resid->stats)(fp32 out).
// XCD-chunked bijective swizzle, y-fastest within each XCD's x-octet.
// ---------------------------------------------------------------------------
__global__ __launch_bounds__(256) void gemm_bt128(
    const ushort* __restrict__ A, const ushort* __restrict__ B,
    const float* __restrict__ bias, ushort* __restrict__ C,
    const ushort* __restrict__ resid, float* __restrict__ stats,
    float* __restrict__ outF, int relu)
{
    __shared__ ushort ldsA[2 * TBUF], ldsB[2 * TBUF];
    __shared__ float sred1[4], sred2[4];
    const int lid = blockIdx.y * 64 + blockIdx.x;
    const int xcd = lid & 7, idx = lid >> 3;          // idx in [0,64)
    const int bx = xcd * 8 + (idx >> 3);              // 8 x-tiles per XCD
    const int by = idx & 7;                           // y fastest
    floatx4 acc[4][4];
#pragma unroll
    for (int i = 0; i < 4; i++)
#pragma unroll
        for (int j = 0; j < 4; j++) acc[i][j] = (floatx4){0.f, 0.f, 0.f, 0.f};

    gemm_core128(A + (size_t)bx * 128 * D_MODEL,
                 B + (size_t)by * 128 * D_MODEL,
                 D_MODEL, D_MODEL, D_MODEL, ldsA, ldsB, acc);

    const int lane = threadIdx.x & 63, w = threadIdx.x >> 6;
    const int wm = w >> 1, wn = w & 1;
    const int mn = lane & 15, quad = lane >> 4;
    float ssum = 0.f, ssq = 0.f;
#pragma unroll
    for (int i = 0; i < 4; i++) {
#pragma unroll
        for (int j = 0; j < 4; j++) {
            int col = by * 128 + wn * 64 + j * 16 + mn;
            float bv = bias ? bias[col] : 0.f;
#pragma unroll
            for (int r = 0; r < 4; r++) {
                int row = bx * 128 + wm * 64 + i * 16 + quad * 4 + r;
                float v = acc[i][j][r] + bv;
                if (relu) v = fmaxf(v, 0.f);
                if (resid) {
                    v += bf2f(resid[(size_t)row * D_MODEL + col]);
                    ssum += v; ssq += v * v;
                }
                if (outF) outF[(size_t)row * D_MODEL + col] = v;
                else      C[(size_t)row * D_MODEL + col] = f2bf(v);
            }
        }
    }
    if (stats) {
        for (int o = 1; o < 64; o <<= 1) {
            ssum += __shfl_xor(ssum, o); ssq += __shfl_xor(ssq, o);
        }
        if (lane == 0) { sred1[w] = ssum; sred2[w] = ssq; }
        __syncthreads();
        if (threadIdx.x == 0) {
            int b = bx >> 3;
            atomicAdd(&stats[b * 32],      sred1[0] + sred1[1] + sred1[2] + sred1[3]);
            atomicAdd(&stats[b * 32 + 16], sred2[0] + sred2[1] + sred2[2] + sred2[3]);
        }
    }
}

// ---------------------------------------------------------------------------
// Fused Q/K/V projection. Q is pre-scaled by 1/8 in the fp32 epilogue (free;
// flash_attn consumes Q/8 directly). V stored transposed with packed 8B stores.
// ---------------------------------------------------------------------------
__global__ __launch_bounds__(256) void gemm_qkv(
    const ushort* __restrict__ X, const ushort* __restrict__ Wq,
    const ushort* __restrict__ Wk, const ushort* __restrict__ Wv,
    ushort* __restrict__ Q, ushort* __restrict__ K, ushort* __restrict__ Vt)
{
    __shared__ ushort ldsA[2 * TBUF], ldsB[2 * TBUF];
    const int lid = blockIdx.y * 64 + blockIdx.x;     // grid (64,24)
    const int xcd = lid & 7, idx = lid >> 3;          // idx in [0,192)
    const int bx = xcd * 8 + idx / 24;                // 8 x-tiles per XCD
    const int byy = idx % 24;                         // y fastest
    const int which = byy >> 3;
    const int nb = byy & 7;
    const ushort* B = (which == 0) ? Wq : (which == 1) ? Wk : Wv;
    floatx4 acc[4][4];
#pragma unroll
    for (int i = 0; i < 4; i++)
#pragma unroll
        for (int j = 0; j < 4; j++) acc[i][j] = (floatx4){0.f, 0.f, 0.f, 0.f};

    gemm_core128(X + (size_t)bx * 128 * D_MODEL,
                 B + (size_t)nb * 128 * D_MODEL,
                 D_MODEL, D_MODEL, D_MODEL, ldsA, ldsB, acc);

    const int lane = threadIdx.x & 63, w = threadIdx.x >> 6;
    const int wm = w >> 1, wn = w & 1;
    const int mn = lane & 15, quad = lane >> 4;
    if (which == 2) {
        // Vt[(b*H+h)*DKV+kk][t]: r = consecutive t -> pack 4 bf16 = 8B store
#pragma unroll
        for (int i = 0; i < 4; i++) {
#pragma unroll
            for (int j = 0; j < 4; j++) {
                int col = nb * 128 + wn * 64 + j * 16 + mn;
                int h = col >> 6, kk = col & 63;
                int row0 = bx * 128 + wm * 64 + i * 16 + quad * 4;
                int b = row0 >> 10, t0 = row0 & 1023;
                uint2 uu;
                uu.x = cvtpk(acc[i][j][0], acc[i][j][1]);
                uu.y = cvtpk(acc[i][j][2], acc[i][j][3]);
                *(uint2*)(Vt + (((size_t)(b * HEADS + h)) * DKV + kk) * SEQ + t0) = uu;
            }
        }
    } else {
        ushort* dst = (which == 0) ? Q : K;
        const float scl = (which == 0) ? 0.125f : 1.0f;   // Q pre-scale (exact pow2)
#pragma unroll
        for (int i = 0; i < 4; i++) {
#pragma unroll
            for (int j = 0; j < 4; j++) {
                int col = nb * 128 + wn * 64 + j * 16 + mn;
#pragma unroll
                for (int r = 0; r < 4; r++) {
                    int row = bx * 128 + wm * 64 + i * 16 + quad * 4 + r;
                    dst[(size_t)row * D_MODEL + col] = f2bf(acc[i][j][r] * scl);
                }
            }
        }
    }
}

// ---------------------------------------------------------------------------
// Flash attention v3: swapped-QK^T + FULL in-register P (T12 permlane), zero
// staging VGPRs (global_load_lds), 32KB LDS -> 3-4 blocks/CU.
//  - Q fragments loaded straight from global (Q pre-scaled 1/8 by gemm_qkv).
//  - K staged folded [64][128] linear, V [64][128] linear, both with 16B-chunk
//    XOR swizzle (chunk ^= row&7): gload_lds-compatible (linear dest +
//    inverse-swizzled per-lane SOURCE + swizzled read), all reads <=2-way.
//  - P redistribution: dest word e2 of frag kk = source cvtpk word (e2&1) of
//    j=2kk+(quad>>1) from lane quad (quad&1)*2+(e2>>1). (A,C)->pl32->pl16
//    gives (R0,R2); (B,D) gives (R1,R3). No LDS, no barriers on P path.
//  - Prefetch in dead windows: lK dead after QK -> stage_K(tk+1) after bar1;
//    lV dead after PV -> stage_V(tk+1) after bar2. Next barrier's implicit
//    vmcnt(0) drains. 2 barriers/tile, loads covered by compute.
// ---------------------------------------------------------------------------
__global__ __launch_bounds__(256) void flash_attn(
    const ushort* __restrict__ Q, const ushort* __restrict__ K,
    const ushort* __restrict__ Vt, ushort* __restrict__ O)
{
    __shared__ ushort lK[64 * 128];   // folded K tile [row&63][(r>>6)*8+ch], 16KB
    __shared__ ushort lV[64 * 128];   // V tile [d][t-chunks], 16KB
    const int tid = threadIdx.x, lane = tid & 63, w = tid >> 6;
    const int mn = lane & 15, quad = lane >> 4;
    const int pair = blockIdx.x;        // 0..127
    const int qt = blockIdx.y;          // 0..7
    const int b = pair >> 4, h = pair & 15;
    const ushort* Qb = Q + ((size_t)b * SEQ) * D_MODEL + h * DKV;
    const ushort* Kb = K + ((size_t)b * SEQ) * D_MODEL + h * DKV;
    const ushort* Vb = Vt + (size_t)pair * DKV * SEQ;

    // Q B-fragments straight from global (already scaled by 1/8)
    short8 bq[2][2];
#pragma unroll
    for (int i = 0; i < 2; i++)
#pragma unroll
        for (int kk = 0; kk < 2; kk++)
            bq[i][kk] = *(const short8*)(Qb +
                (size_t)(qt * 128 + w * 32 + i * 16 + mn) * D_MODEL + kk * 32 + quad * 8);

    // staging: K tile tkk -> lK (folded+swizzled), V tile tkk -> lV (swizzled)
    auto stage_K = [&](int tkk) {
#pragma unroll
        for (int c = 0; c < 4; c++) {
            int lin = c * 256 + tid;          // 16B chunk index 0..1023
            int rw = lin >> 4;                // folded row' 0..63
            int cc0 = (lin & 15) ^ (rw & 7);  // unswizzled chunk
            int r = rw + ((cc0 >> 3) << 6);   // orig key-row 0..127
            gload16(Kb + (size_t)(tkk * 128 + r) * D_MODEL + (cc0 & 7) * 8,
                    lK + lin * 8);
        }
    };
    auto stage_V = [&](int tkk) {
#pragma unroll
        for (int c = 0; c < 4; c++) {
            int lin = c * 256 + tid;
            int rw = lin >> 4;                // d-row 0..63
            int cc0 = (lin & 15) ^ (rw & 7);
            gload16(Vb + (size_t)rw * SEQ + tkk * 128 + cc0 * 8,
                    lV + lin * 8);
        }
    };

    stage_K(0); stage_V(0);
    __syncthreads();                          // drains vmcnt: tile 0 ready

    floatx4 acc_o[2][4];
    float lrow[2] = {0.f, 0.f};
#pragma unroll
    for (int i = 0; i < 2; i++)
#pragma unroll
        for (int jo = 0; jo < 4; jo++) acc_o[i][jo] = (floatx4){0.f, 0.f, 0.f, 0.f};

    for (int tk = 0; tk < 8; tk++) {
        // ---- QK: S^T = mfma(K, Q/8); s[i][j][r] = S[key=j*16+quad*4+r][q=w*32+i*16+mn]
        floatx4 s[2][8];
#pragma unroll
        for (int i = 0; i < 2; i++)
#pragma unroll
            for (int j = 0; j < 8; j++) s[i][j] = (floatx4){0.f, 0.f, 0.f, 0.f};
        __builtin_amdgcn_s_setprio(1);
#pragma unroll
        for (int kk = 0; kk < 2; kk++) {
#pragma unroll
            for (int j = 0; j < 8; j++) {
                int krow = (j & 3) * 16 + mn;                       // (j*16+mn)&63
                int kch = (((j >> 2) * 8 + kk * 4 + quad) ^ (mn & 7));
                short8 ak = *(const short8*)(lK + krow * 128 + kch * 8);
                s[0][j] = __builtin_amdgcn_mfma_f32_16x16x32_bf16(ak, bq[0][kk], s[0][j], 0, 0, 0);
                s[1][j] = __builtin_amdgcn_mfma_f32_16x16x32_bf16(ak, bq[1][kk], s[1][j], 0, 0, 0);
            }
        }
        __builtin_amdgcn_s_setprio(0);
        __syncthreads();                      // all waves done reading lK
        if (tk < 7) stage_K(tk + 1);          // lands by next syncthreads

        // ---- softmax numerator (no max shift, bounded scores) + bf16 pack
        uint pw[2][8][2];
#pragma unroll
        for (int i = 0; i < 2; i++) {
            float ps = 0.f;
#pragma unroll
            for (int j = 0; j < 8; j++) {
                float p0 = __expf(s[i][j][0]), p1 = __expf(s[i][j][1]);
                float p2 = __expf(s[i][j][2]), p3 = __expf(s[i][j][3]);
                ps += (p0 + p1) + (p2 + p3);
                pw[i][j][0] = cvtpk(p0, p1);
                pw[i][j][1] = cvtpk(p2, p3);
            }
            ps += __shfl_xor(ps, 16);
            ps += __shfl_xor(ps, 32);
            lrow[i] += ps;
        }

        // ---- PV: in-register P redistribution + MFMA
        __builtin_amdgcn_s_setprio(1);
#pragma unroll
        for (int kk = 0; kk < 4; kk++) {
            union { short8 s8; uint u[4]; } pa[2];
#pragma unroll
            for (int i = 0; i < 2; i++) {
                uint A = pw[i][2 * kk][0],     Bw = pw[i][2 * kk][1];
                uint C = pw[i][2 * kk + 1][0], D  = pw[i][2 * kk + 1][1];
                pl32(A, C);  pl16(A, C);      // A->R0, C->R2
                pl32(Bw, D); pl16(Bw, D);     // B->R1, D->R3
                pa[i].u[0] = A; pa[i].u[1] = Bw; pa[i].u[2] = C; pa[i].u[3] = D;
            }
#pragma unroll
            for (int jo = 0; jo < 4; jo++) {
                int vch = ((kk * 4 + quad) ^ (mn & 7));
                short8 bv = *(const short8*)(lV + (jo * 16 + mn) * 128 + vch * 8);
                acc_o[0][jo] = __builtin_amdgcn_mfma_f32_16x16x32_bf16(pa[0].s8, bv, acc_o[0][jo], 0, 0, 0);
                acc_o[1][jo] = __builtin_amdgcn_mfma_f32_16x16x32_bf16(pa[1].s8, bv, acc_o[1][jo], 0, 0, 0);
            }
        }
        __builtin_amdgcn_s_setprio(0);
        __syncthreads();                      // all waves done reading lV; K landed
        if (tk < 7) stage_V(tk + 1);          // lands by next post-QK syncthreads
    }

    // epilogue: O = acc_o / l. acc_o[i][jo][r] = O[q=w*32+i*16+quad*4+r][d=jo*16+mn];
    // row-sum for q-row t lives in lanes with mn==t -> fetch via shuffle.
#pragma unroll
    for (int i = 0; i < 2; i++)
#pragma unroll
        for (int r = 0; r < 4; r++) {
            float rs = __shfl(lrow[i], quad * 4 + r);
            float rinv = 1.f / rs;
            int row = qt * 128 + w * 32 + i * 16 + quad * 4 + r;
#pragma unroll
            for (int jo = 0; jo < 4; jo++)
                O[((size_t)b * SEQ + row) * D_MODEL + h * DKV + jo * 16 + mn] =
                    f2bf(acc_o[i][jo][r] * rinv);
        }
}

// ---------------------------------------------------------------------------
// fp32 -> bf16 bulk convert
__global__ __launch_bounds__(256) void cvt_f32_bf16(const float* __restrict__ src,
                                                    ushort* __restrict__ dst) {
    size_t base = ((size_t)blockIdx.x * 256 + threadIdx.x) * 8;
    float4 a = *(const float4*)(src + base);
    float4 b = *(const float4*)(src + base + 4);
    short8 o;
    o[0] = (short)f2bf(a.x); o[1] = (short)f2bf(a.y);
    o[2] = (short)f2bf(a.z); o[3] = (short)f2bf(a.w);
    o[4] = (short)f2bf(b.x); o[5] = (short)f2bf(b.y);
    o[6] = (short)f2bf(b.z); o[7] = (short)f2bf(b.w);
    *(short8*)(dst + base) = o;
}

// x = X + positional encoding (base 1000, per reference). fp32 in, bf16 out.
__global__ __launch_bounds__(256) void add_pos(const float* __restrict__ X,
                                               ushort* __restrict__ x) {
    size_t idx = (size_t)blockIdx.x * 256 + threadIdx.x;
    int d = (int)(idx & (D_MODEL - 1));
    int s = (int)((idx >> 10) & (SEQ - 1));
    float freq = powf(1000.f, (float)(2 * (d >> 1)) * (1.f / (float)D_MODEL));
    float ang = (float)s / freq;
    float pe = (d & 1) ? cosf(ang) : sinf(ang);
    x[idx] = f2bf(X[idx] + pe);
}

__global__ __launch_bounds__(256) void ln_apply(
    const ushort* __restrict__ S, ushort* __restrict__ Y,
    const float* __restrict__ stats)
{
    size_t base = ((size_t)blockIdx.x * 256 + threadIdx.x) * 8;
    int b = blockIdx.x >> 9;
    float mean = stats[b * 32] * (1.f / (float)LN_N);
    float var = stats[b * 32 + 16] * (1.f / (float)LN_N) - mean * mean;
    float r = rsqrtf(var + EPSV);
    short8 sv = *(const short8*)(S + base);
    short8 ov;
#pragma unroll
    for (int i = 0; i < 8; i++) ov[i] = (short)f2bf((bf2f((ushort)sv[i]) - mean) * r);
    *(short8*)(Y + base) = ov;
}

__global__ void zero_stats(float* stats) { stats[threadIdx.x] = 0.f; }  // 256 thr

// ---------------------------------------------------------------------------
extern "C" void kernel_launch(void* const* d_in, const int* in_sizes, int n_in,
                              void* d_out, int out_size, void* d_ws, size_t ws_size,
                              hipStream_t stream) {
    const float* X    = (const float*)d_in[0];
    const float* Wq   = (const float*)d_in[1];
    const float* Wk   = (const float*)d_in[2];
    const float* Wv   = (const float*)d_in[3];
    const float* W0   = (const float*)d_in[4];
    const float* Wr_w = (const float*)d_in[5];
    const float* Wr_b = (const float*)d_in[6];
    const float* Wf0w = (const float*)d_in[7];
    const float* Wf0b = (const float*)d_in[8];
    const float* Wf1w = (const float*)d_in[9];
    const float* Wf1b = (const float*)d_in[10];
    float* out = (float*)d_out;

    char* ws = (char*)d_ws;
    size_t off = 0;
    auto alloc = [&](size_t bytes) -> void* {
        void* p = ws + off; off += (bytes + 255) & ~(size_t)255; return p;
    };
    const size_t ACT = (size_t)NTOK * D_MODEL * sizeof(ushort);     // 16 MB
    const size_t WTE = (size_t)LAYERS * D_MODEL * D_MODEL;          // elements/weight tensor
    ushort* x  = (ushort*)alloc(ACT);
    ushort* bQ = (ushort*)alloc(ACT);
    ushort* bK = (ushort*)alloc(ACT);
    ushort* bV = (ushort*)alloc(ACT);   // Vt: [B][H][DK][SEQ]
    ushort* bO = (ushort*)alloc(ACT);
    ushort* wq  = (ushort*)alloc(WTE * 2);
    ushort* wk  = (ushort*)alloc(WTE * 2);
    ushort* wv  = (ushort*)alloc(WTE * 2);
    ushort* w0  = (ushort*)alloc(WTE * 2);
    ushort* wr  = (ushort*)alloc(WTE * 2);
    ushort* wf0 = (ushort*)alloc(WTE * 2);
    ushort* wf1 = (ushort*)alloc(WTE * 2);
    float* stats = (float*)alloc(256 * sizeof(float));

    const int EW_BLOCKS = (NTOK * D_MODEL) / (256 * 8);        // 4096
    const int CVT_BLOCKS = (int)(WTE / (256 * 8));             // 2048
    const dim3 GEMM_GRID(NTOK / 128, D_MODEL / 128);           // (64, 8)
    const dim3 QKV_GRID(NTOK / 128, 3 * D_MODEL / 128);        // (64, 24)
    const dim3 FLASH_GRID(BATCH * HEADS, SEQ / 128);           // (128, 8)

    cvt_f32_bf16<<<CVT_BLOCKS, 256, 0, stream>>>(Wq,   wq);
    cvt_f32_bf16<<<CVT_BLOCKS, 256, 0, stream>>>(Wk,   wk);
    cvt_f32_bf16<<<CVT_BLOCKS, 256, 0, stream>>>(Wv,   wv);
    cvt_f32_bf16<<<CVT_BLOCKS, 256, 0, stream>>>(W0,   w0);
    cvt_f32_bf16<<<CVT_BLOCKS, 256, 0, stream>>>(Wr_w, wr);
    cvt_f32_bf16<<<CVT_BLOCKS, 256, 0, stream>>>(Wf0w, wf0);
    cvt_f32_bf16<<<CVT_BLOCKS, 256, 0, stream>>>(Wf1w, wf1);

    add_pos<<<(NTOK * D_MODEL) / 256, 256, 0, stream>>>(X, x);

    for (int l = 0; l < LAYERS; l++) {
        const size_t WO = (size_t)l * D_MODEL * D_MODEL;
        const ushort* Wq_l  = wq  + WO;
        const ushort* Wk_l  = wk  + WO;
        const ushort* Wv_l  = wv  + WO;
        const ushort* W0_l  = w0  + WO;
        const ushort* Wr_l  = wr  + WO;
        const ushort* W0w_l = wf0 + WO;
        const ushort* W1w_l = wf1 + WO;
        const float* Wrb_l = Wr_b + (size_t)l * D_MODEL;
        const float* W0b_l = Wf0b + (size_t)l * D_MODEL;
        const float* W1b_l = Wf1b + (size_t)l * D_MODEL;

        // Q,K,V projections (fused; Q pre-scaled by 1/8)
        gemm_qkv<<<QKV_GRID, 256, 0, stream>>>(x, Wq_l, Wk_l, Wv_l, bQ, bK, bV);

        flash_attn<<<FLASH_GRID, 256, 0, stream>>>(bQ, bK, bV, bO);

        // s1 = x + O@W0^T -> bK, + LN stats (fused epilogue)
        zero_stats<<<1, 256, 0, stream>>>(stats);
        gemm_bt128<<<GEMM_GRID, 256, 0, stream>>>(bO, W0_l, nullptr, bK,
            x, stats, nullptr, 0);
        // y1 = LN(s1) -> bO
        ln_apply<<<EW_BLOCKS, 256, 0, stream>>>(bK, bO, stats);
        // r0 = y1 @ Wr^T + br -> bV
        gemm_bt128<<<GEMM_GRID, 256, 0, stream>>>(bO, Wr_l, Wrb_l, bV,
            nullptr, nullptr, nullptr, 0);
        // h0 = relu(r0 @ Wf0^T + b0) -> bQ
        gemm_bt128<<<GEMM_GRID, 256, 0, stream>>>(bV, W0w_l, W0b_l, bQ,
            nullptr, nullptr, nullptr, 1);
        // s2 = r0 + h0 @ Wf1^T + b1 -> bK, + LN stats (fused)
        zero_stats<<<1, 256, 0, stream>>>(stats);
        gemm_bt128<<<GEMM_GRID, 256, 0, stream>>>(bQ, W1w_l, W1b_l, bK,
            bV, stats, nullptr, 0);
        // y2 = LN(s2) -> bO
        ln_apply<<<EW_BLOCKS, 256, 0, stream>>>(bK, bO, stats);
        // x = y2 @ Wr^T + br -> x (last layer: write fp32 directly to d_out)
        gemm_bt128<<<GEMM_GRID, 256, 0, stream>>>(bO, Wr_l, Wrb_l, x,
            nullptr, nullptr, (l == LAYERS - 1) ? out : nullptr, 0);
    }
}

// Round 4
// 1334.996 us; speedup vs baseline: 1.2205x; 1.1246x over previous
//
#include <hip/hip_runtime.h>
#include <hip/hip_bf16.h>
#include <math.h>

// Problem constants (Encoder_16750372454478)
#define D_MODEL 1024
#define HEADS   16
#define DKV     64
#define LAYERS  4
#define BATCH   8
#define SEQ     1024
#define NTOK    (BATCH*SEQ)      // 8192
#define LN_N    (SEQ*D_MODEL)    // per-sample LN element count
#define EPSV    1e-5f

typedef __attribute__((ext_vector_type(8))) short short8;   // 8 bf16 (4 VGPRs)
typedef __attribute__((ext_vector_type(4))) float floatx4;

__device__ __forceinline__ float bf2f(ushort u) {
    union { uint i; float f; } v; v.i = ((uint)u) << 16; return v.f;
}
__device__ __forceinline__ ushort f2bf(float f) {
    union { float f; uint i; } v; v.f = f;
    uint r = (v.i + 0x7fffu + ((v.i >> 16) & 1u)) >> 16;   // round-nearest-even
    return (ushort)r;
}
// pack two f32 -> one u32 of 2 bf16 (low = a, high = b). T12 recipe (no builtin).
__device__ __forceinline__ uint cvtpk(float a, float b) {
    uint r;
    asm("v_cvt_pk_bf16_f32 %0, %1, %2" : "=v"(r) : "v"(a), "v"(b));
    return r;
}
// permlane swaps (gfx950): a/c both read+written.
__device__ __forceinline__ void pl32(uint &a, uint &c) {
    asm volatile("v_permlane32_swap_b32 %0, %1" : "+v"(a), "+v"(c));
}
__device__ __forceinline__ void pl16(uint &a, uint &c) {
    asm volatile("v_permlane16_swap_b32 %0, %1" : "+v"(a), "+v"(c));
}

// async global->LDS, 16 B per lane (LDS dest = wave-uniform base + lane*16).
__device__ __forceinline__ void gload16(const ushort* g, ushort* l) {
    __builtin_amdgcn_global_load_lds(
        (const __attribute__((address_space(1))) void*)g,
        (__attribute__((address_space(3))) void*)l, 16, 0, 0);
}

// ---------------------------------------------------------------------------
// GEMM core, 2-phase double-buffered, templated K-step. C[128x128], 4 waves
// (2x2), 64x64 each. Staging via global_load_lds with BOTH-SIDES XOR swizzle
// (rule #21): linear LDS dest + inverse-swizzled per-lane GLOBAL source +
// swizzled ds_read. Read conflicts: BK=64 -> 2-way (free), BK=32 -> 4-way.
// ---------------------------------------------------------------------------
template<int BK>
__device__ __forceinline__ void gemm_coreT(
    const ushort* __restrict__ A, const ushort* __restrict__ B,
    int lda, int ldb, int Kd,
    ushort* ldsA, ushort* ldsB, floatx4 (&acc)[4][4])
{
    constexpr int CH = BK / 8;            // 16B chunks per row
    constexpr int TB = 128 * BK;          // elements per buffer
    const int tid  = threadIdx.x;
    const int lane = tid & 63;
    const int w    = tid >> 6;
    const int wm   = w >> 1, wn = w & 1;
    const int mn   = lane & 15, quad = lane >> 4;

    auto stage = [&](int k0, int buf) {
#pragma unroll
        for (int s = 0; s < CH / 2; s++) {
            int lin = s * 256 + tid;          // chunk index in tile
            int r   = lin / CH;               // row 0..127
            int cp  = lin % CH;               // physical chunk
            int cs_ = cp ^ (r & (CH - 1));    // source chunk (involution)
            gload16(A + (size_t)r * lda + k0 + cs_ * 8, ldsA + buf * TB + lin * 8);
            gload16(B + (size_t)r * ldb + k0 + cs_ * 8, ldsB + buf * TB + lin * 8);
        }
    };

    stage(0, 0);
    __syncthreads();

    int cur = 0;
    for (int k0 = 0; k0 < Kd; k0 += BK) {
        if (k0 + BK < Kd) stage(k0 + BK, cur ^ 1);   // fly under MFMA phase
        const ushort* cA = ldsA + cur * TB;
        const ushort* cB = ldsB + cur * TB;
#pragma unroll
        for (int kk = 0; kk < BK / 32; kk++) {
            short8 af[4], bfr[4];
#pragma unroll
            for (int i = 0; i < 4; i++) {
                int r = wm * 64 + i * 16 + mn;
                int c = (kk * 4 + quad) ^ (r & (CH - 1));
                af[i] = *(const short8*)(cA + r * BK + c * 8);
            }
#pragma unroll
            for (int j = 0; j < 4; j++) {
                int r = wn * 64 + j * 16 + mn;
                int c = (kk * 4 + quad) ^ (r & (CH - 1));
                bfr[j] = *(const short8*)(cB + r * BK + c * 8);
            }
#pragma unroll
            for (int i = 0; i < 4; i++)
#pragma unroll
                for (int j = 0; j < 4; j++)
                    acc[i][j] = __builtin_amdgcn_mfma_f32_16x16x32_bf16(af[i], bfr[j], acc[i][j], 0, 0, 0);
        }
        __syncthreads();   // implicit vmcnt(0): next tile landed; buf swap safe
        cur ^= 1;
    }
}

// ---------------------------------------------------------------------------
// Generic GEMM: out = f(A[M,K] B[N,K]^T) with optional fused epilogues:
//  - lnIn+csum: A is a raw pre-LN activation; apply LN algebraically:
//      out = r*(acc - mean*colsum_j) + bias_j   (mean,r per-sample from lnIn)
//  - bias, relu
//  - resid: v += resid[elem]; per-sample sum/sumsq atomically -> statsOut
//  - outF: write fp32 instead of bf16
// XCD-chunked swizzle, y-fastest. BK=64 (grid-capped 2 blocks/CU; 64KB LDS).
// stats layout: base[smp] = sum, base[32+smp] = sumsq.
// ---------------------------------------------------------------------------
__global__ __launch_bounds__(256) void gemm_bt128(
    const ushort* __restrict__ A, const ushort* __restrict__ B,
    const float* __restrict__ bias, ushort* __restrict__ C,
    const ushort* __restrict__ resid, float* __restrict__ statsOut,
    float* __restrict__ outF, int relu,
    const float* __restrict__ lnIn, const float* __restrict__ csum)
{
    __shared__ ushort ldsA[2 * 128 * 64], ldsB[2 * 128 * 64];
    __shared__ float sred1[4], sred2[4];
    const int lid = blockIdx.y * 64 + blockIdx.x;
    const int xcd = lid & 7, idx = lid >> 3;          // idx in [0,64)
    const int bx = xcd * 8 + (idx >> 3);              // 8 x-tiles per XCD
    const int by = idx & 7;                           // y fastest
    floatx4 acc[4][4];
#pragma unroll
    for (int i = 0; i < 4; i++)
#pragma unroll
        for (int j = 0; j < 4; j++) acc[i][j] = (floatx4){0.f, 0.f, 0.f, 0.f};

    gemm_coreT<64>(A + (size_t)bx * 128 * D_MODEL,
                   B + (size_t)by * 128 * D_MODEL,
                   D_MODEL, D_MODEL, D_MODEL, ldsA, ldsB, acc);

    const int lane = threadIdx.x & 63, w = threadIdx.x >> 6;
    const int wm = w >> 1, wn = w & 1;
    const int mn = lane & 15, quad = lane >> 4;
    const int bsmp = bx >> 3;                         // sample (128 | SEQ)
    float mean = 0.f, rln = 1.f;
    if (lnIn) {
        float sum = lnIn[bsmp], sq = lnIn[32 + bsmp];
        mean = sum * (1.f / (float)LN_N);
        rln  = rsqrtf(sq * (1.f / (float)LN_N) - mean * mean + EPSV);
    }
    float ssum = 0.f, ssq = 0.f;
#pragma unroll
    for (int i = 0; i < 4; i++) {
#pragma unroll
        for (int j = 0; j < 4; j++) {
            int col = by * 128 + wn * 64 + j * 16 + mn;
            float bv = bias ? bias[col] : 0.f;
            float cj = csum ? csum[col] : 0.f;
#pragma unroll
            for (int r = 0; r < 4; r++) {
                int row = bx * 128 + wm * 64 + i * 16 + quad * 4 + r;
                float v = acc[i][j][r];
                if (lnIn) v = (v - mean * cj) * rln;
                v += bv;
                if (relu) v = fmaxf(v, 0.f);
                if (resid) {
                    v += bf2f(resid[(size_t)row * D_MODEL + col]);
                    ssum += v; ssq += v * v;
                }
                if (outF) outF[(size_t)row * D_MODEL + col] = v;
                else      C[(size_t)row * D_MODEL + col] = f2bf(v);
            }
        }
    }
    if (statsOut) {
        for (int o = 1; o < 64; o <<= 1) {
            ssum += __shfl_xor(ssum, o); ssq += __shfl_xor(ssq, o);
        }
        if (lane == 0) { sred1[w] = ssum; sred2[w] = ssq; }
        __syncthreads();
        if (threadIdx.x == 0) {
            atomicAdd(&statsOut[bsmp],      sred1[0] + sred1[1] + sred1[2] + sred1[3]);
            atomicAdd(&statsOut[32 + bsmp], sred2[0] + sred2[1] + sred2[2] + sred2[3]);
        }
    }
}

// ---------------------------------------------------------------------------
// Fused Q/K/V projection. Q pre-scaled by 1/8 in the fp32 epilogue. V stored
// transposed per head with packed 8B stores. BK=32 (32KB LDS, 5 blocks/CU).
// ---------------------------------------------------------------------------
__global__ __launch_bounds__(256) void gemm_qkv(
    const ushort* __restrict__ X, const ushort* __restrict__ Wq,
    const ushort* __restrict__ Wk, const ushort* __restrict__ Wv,
    ushort* __restrict__ Q, ushort* __restrict__ K, ushort* __restrict__ Vt)
{
    __shared__ ushort ldsA[2 * 128 * 32], ldsB[2 * 128 * 32];
    const int lid = blockIdx.y * 64 + blockIdx.x;     // grid (64,24)
    const int xcd = lid & 7, idx = lid >> 3;          // idx in [0,192)
    const int bx = xcd * 8 + idx / 24;                // 8 x-tiles per XCD
    const int byy = idx % 24;                         // y fastest
    const int which = byy >> 3;
    const int nb = byy & 7;
    const ushort* B = (which == 0) ? Wq : (which == 1) ? Wk : Wv;
    floatx4 acc[4][4];
#pragma unroll
    for (int i = 0; i < 4; i++)
#pragma unroll
        for (int j = 0; j < 4; j++) acc[i][j] = (floatx4){0.f, 0.f, 0.f, 0.f};

    gemm_coreT<32>(X + (size_t)bx * 128 * D_MODEL,
                   B + (size_t)nb * 128 * D_MODEL,
                   D_MODEL, D_MODEL, D_MODEL, ldsA, ldsB, acc);

    const int lane = threadIdx.x & 63, w = threadIdx.x >> 6;
    const int wm = w >> 1, wn = w & 1;
    const int mn = lane & 15, quad = lane >> 4;
    if (which == 2) {
        // Vt[(b*H+h)*DKV+kk][t]: r = consecutive t -> pack 4 bf16 = 8B store
#pragma unroll
        for (int i = 0; i < 4; i++) {
#pragma unroll
            for (int j = 0; j < 4; j++) {
                int col = nb * 128 + wn * 64 + j * 16 + mn;
                int h = col >> 6, kk = col & 63;
                int row0 = bx * 128 + wm * 64 + i * 16 + quad * 4;
                int b = row0 >> 10, t0 = row0 & 1023;
                uint2 uu;
                uu.x = cvtpk(acc[i][j][0], acc[i][j][1]);
                uu.y = cvtpk(acc[i][j][2], acc[i][j][3]);
                *(uint2*)(Vt + (((size_t)(b * HEADS + h)) * DKV + kk) * SEQ + t0) = uu;
            }
        }
    } else {
        ushort* dst = (which == 0) ? Q : K;
        const float scl = (which == 0) ? 0.125f : 1.0f;   // Q pre-scale (exact pow2)
#pragma unroll
        for (int i = 0; i < 4; i++) {
#pragma unroll
            for (int j = 0; j < 4; j++) {
                int col = nb * 128 + wn * 64 + j * 16 + mn;
#pragma unroll
                for (int r = 0; r < 4; r++) {
                    int row = bx * 128 + wm * 64 + i * 16 + quad * 4 + r;
                    dst[(size_t)row * D_MODEL + col] = f2bf(acc[i][j][r] * scl);
                }
            }
        }
    }
}

// ---------------------------------------------------------------------------
// Flash attention v3 (unchanged from round 3): swapped-QK^T + in-register P
// (permlane), zero staging VGPRs (global_load_lds), 32KB LDS.
// ---------------------------------------------------------------------------
__global__ __launch_bounds__(256) void flash_attn(
    const ushort* __restrict__ Q, const ushort* __restrict__ K,
    const ushort* __restrict__ Vt, ushort* __restrict__ O)
{
    __shared__ ushort lK[64 * 128];   // folded K tile, 16KB
    __shared__ ushort lV[64 * 128];   // V tile, 16KB
    const int tid = threadIdx.x, lane = tid & 63, w = tid >> 6;
    const int mn = lane & 15, quad = lane >> 4;
    const int pair = blockIdx.x;        // 0..127
    const int qt = blockIdx.y;          // 0..7
    const int b = pair >> 4, h = pair & 15;
    const ushort* Qb = Q + ((size_t)b * SEQ) * D_MODEL + h * DKV;
    const ushort* Kb = K + ((size_t)b * SEQ) * D_MODEL + h * DKV;
    const ushort* Vb = Vt + (size_t)pair * DKV * SEQ;

    // Q B-fragments straight from global (already scaled by 1/8)
    short8 bq[2][2];
#pragma unroll
    for (int i = 0; i < 2; i++)
#pragma unroll
        for (int kk = 0; kk < 2; kk++)
            bq[i][kk] = *(const short8*)(Qb +
                (size_t)(qt * 128 + w * 32 + i * 16 + mn) * D_MODEL + kk * 32 + quad * 8);

    auto stage_K = [&](int tkk) {
#pragma unroll
        for (int c = 0; c < 4; c++) {
            int lin = c * 256 + tid;          // 16B chunk index 0..1023
            int rw = lin >> 4;                // folded row' 0..63
            int cc0 = (lin & 15) ^ (rw & 7);  // unswizzled chunk
            int r = rw + ((cc0 >> 3) << 6);   // orig key-row 0..127
            gload16(Kb + (size_t)(tkk * 128 + r) * D_MODEL + (cc0 & 7) * 8,
                    lK + lin * 8);
        }
    };
    auto stage_V = [&](int tkk) {
#pragma unroll
        for (int c = 0; c < 4; c++) {
            int lin = c * 256 + tid;
            int rw = lin >> 4;                // d-row 0..63
            int cc0 = (lin & 15) ^ (rw & 7);
            gload16(Vb + (size_t)rw * SEQ + tkk * 128 + cc0 * 8,
                    lV + lin * 8);
        }
    };

    stage_K(0); stage_V(0);
    __syncthreads();

    floatx4 acc_o[2][4];
    float lrow[2] = {0.f, 0.f};
#pragma unroll
    for (int i = 0; i < 2; i++)
#pragma unroll
        for (int jo = 0; jo < 4; jo++) acc_o[i][jo] = (floatx4){0.f, 0.f, 0.f, 0.f};

    for (int tk = 0; tk < 8; tk++) {
        // ---- QK: S^T = mfma(K, Q/8)
        floatx4 s[2][8];
#pragma unroll
        for (int i = 0; i < 2; i++)
#pragma unroll
            for (int j = 0; j < 8; j++) s[i][j] = (floatx4){0.f, 0.f, 0.f, 0.f};
        __builtin_amdgcn_s_setprio(1);
#pragma unroll
        for (int kk = 0; kk < 2; kk++) {
#pragma unroll
            for (int j = 0; j < 8; j++) {
                int krow = (j & 3) * 16 + mn;
                int kch = (((j >> 2) * 8 + kk * 4 + quad) ^ (mn & 7));
                short8 ak = *(const short8*)(lK + krow * 128 + kch * 8);
                s[0][j] = __builtin_amdgcn_mfma_f32_16x16x32_bf16(ak, bq[0][kk], s[0][j], 0, 0, 0);
                s[1][j] = __builtin_amdgcn_mfma_f32_16x16x32_bf16(ak, bq[1][kk], s[1][j], 0, 0, 0);
            }
        }
        __builtin_amdgcn_s_setprio(0);
        __syncthreads();
        if (tk < 7) stage_K(tk + 1);

        // ---- softmax numerator + bf16 pack
        uint pw[2][8][2];
#pragma unroll
        for (int i = 0; i < 2; i++) {
            float ps = 0.f;
#pragma unroll
            for (int j = 0; j < 8; j++) {
                float p0 = __expf(s[i][j][0]), p1 = __expf(s[i][j][1]);
                float p2 = __expf(s[i][j][2]), p3 = __expf(s[i][j][3]);
                ps += (p0 + p1) + (p2 + p3);
                pw[i][j][0] = cvtpk(p0, p1);
                pw[i][j][1] = cvtpk(p2, p3);
            }
            ps += __shfl_xor(ps, 16);
            ps += __shfl_xor(ps, 32);
            lrow[i] += ps;
        }

        // ---- PV: in-register P redistribution + MFMA
        __builtin_amdgcn_s_setprio(1);
#pragma unroll
        for (int kk = 0; kk < 4; kk++) {
            union { short8 s8; uint u[4]; } pa[2];
#pragma unroll
            for (int i = 0; i < 2; i++) {
                uint A = pw[i][2 * kk][0],     Bw = pw[i][2 * kk][1];
                uint C = pw[i][2 * kk + 1][0], D  = pw[i][2 * kk + 1][1];
                pl32(A, C);  pl16(A, C);
                pl32(Bw, D); pl16(Bw, D);
                pa[i].u[0] = A; pa[i].u[1] = Bw; pa[i].u[2] = C; pa[i].u[3] = D;
            }
#pragma unroll
            for (int jo = 0; jo < 4; jo++) {
                int vch = ((kk * 4 + quad) ^ (mn & 7));
                short8 bv = *(const short8*)(lV + (jo * 16 + mn) * 128 + vch * 8);
                acc_o[0][jo] = __builtin_amdgcn_mfma_f32_16x16x32_bf16(pa[0].s8, bv, acc_o[0][jo], 0, 0, 0);
                acc_o[1][jo] = __builtin_amdgcn_mfma_f32_16x16x32_bf16(pa[1].s8, bv, acc_o[1][jo], 0, 0, 0);
            }
        }
        __builtin_amdgcn_s_setprio(0);
        __syncthreads();
        if (tk < 7) stage_V(tk + 1);
    }

    // epilogue: O = acc_o / l
#pragma unroll
    for (int i = 0; i < 2; i++)
#pragma unroll
        for (int r = 0; r < 4; r++) {
            float rs = __shfl(lrow[i], quad * 4 + r);
            float rinv = 1.f / rs;
            int row = qt * 128 + w * 32 + i * 16 + quad * 4 + r;
#pragma unroll
            for (int jo = 0; jo < 4; jo++)
                O[((size_t)b * SEQ + row) * D_MODEL + h * DKV + jo * 16 + mn] =
                    f2bf(acc_o[i][jo][r] * rinv);
        }
}

// ---------------------------------------------------------------------------
// fp32 -> bf16 bulk convert
__global__ __launch_bounds__(256) void cvt_f32_bf16(const float* __restrict__ src,
                                                    ushort* __restrict__ dst) {
    size_t base = ((size_t)blockIdx.x * 256 + threadIdx.x) * 8;
    float4 a = *(const float4*)(src + base);
    float4 b = *(const float4*)(src + base + 4);
    short8 o;
    o[0] = (short)f2bf(a.x); o[1] = (short)f2bf(a.y);
    o[2] = (short)f2bf(a.z); o[3] = (short)f2bf(a.w);
    o[4] = (short)f2bf(b.x); o[5] = (short)f2bf(b.y);
    o[6] = (short)f2bf(b.z); o[7] = (short)f2bf(b.w);
    *(short8*)(dst + base) = o;
}

// x = X + positional encoding (base 1000, per reference). fp32 in, bf16 out.
__global__ __launch_bounds__(256) void add_pos(const float* __restrict__ X,
                                               ushort* __restrict__ x) {
    size_t idx = (size_t)blockIdx.x * 256 + threadIdx.x;
    int d = (int)(idx & (D_MODEL - 1));
    int s = (int)((idx >> 10) & (SEQ - 1));
    float freq = powf(1000.f, (float)(2 * (d >> 1)) * (1.f / (float)D_MODEL));
    float ang = (float)s / freq;
    float pe = (d & 1) ? cosf(ang) : sinf(ang);
    x[idx] = f2bf(X[idx] + pe);
}

// per-row sum of bf16 weight matrix rows (colsum of W^T): cs[row]=sum_k W[row][k]
__global__ __launch_bounds__(256) void colsum_k(const ushort* __restrict__ W,
                                                float* __restrict__ cs) {
    int row = blockIdx.x * 4 + (threadIdx.x >> 6);
    int lane = threadIdx.x & 63;
    const ushort* Wr = W + (size_t)row * D_MODEL;
    float s = 0.f;
#pragma unroll
    for (int p = 0; p < 2; p++) {
        short8 v = *(const short8*)(Wr + p * 512 + lane * 8);
#pragma unroll
        for (int e = 0; e < 8; e++) s += bf2f((ushort)v[e]);
    }
#pragma unroll
    for (int o = 1; o < 64; o <<= 1) s += __shfl_xor(s, o);
    if (lane == 0) cs[row] = s;
}

__global__ void zero_stats512(float* stats) {   // 8 instances x 64 floats
    stats[threadIdx.x] = 0.f; stats[256 + threadIdx.x] = 0.f;
}

// ---------------------------------------------------------------------------
extern "C" void kernel_launch(void* const* d_in, const int* in_sizes, int n_in,
                              void* d_out, int out_size, void* d_ws, size_t ws_size,
                              hipStream_t stream) {
    const float* X    = (const float*)d_in[0];
    const float* Wq   = (const float*)d_in[1];
    const float* Wk   = (const float*)d_in[2];
    const float* Wv   = (const float*)d_in[3];
    const float* W0   = (const float*)d_in[4];
    const float* Wr_w = (const float*)d_in[5];
    const float* Wr_b = (const float*)d_in[6];
    const float* Wf0w = (const float*)d_in[7];
    const float* Wf0b = (const float*)d_in[8];
    const float* Wf1w = (const float*)d_in[9];
    const float* Wf1b = (const float*)d_in[10];
    float* out = (float*)d_out;

    char* ws = (char*)d_ws;
    size_t off = 0;
    auto alloc = [&](size_t bytes) -> void* {
        void* p = ws + off; off += (bytes + 255) & ~(size_t)255; return p;
    };
    const size_t ACT = (size_t)NTOK * D_MODEL * sizeof(ushort);     // 16 MB
    const size_t WTE = (size_t)LAYERS * D_MODEL * D_MODEL;          // elements/weight tensor
    ushort* x  = (ushort*)alloc(ACT);
    ushort* bQ = (ushort*)alloc(ACT);
    ushort* bK = (ushort*)alloc(ACT);
    ushort* bV = (ushort*)alloc(ACT);   // Vt: [B][H][DK][SEQ]
    ushort* bO = (ushort*)alloc(ACT);
    ushort* wq  = (ushort*)alloc(WTE * 2);
    ushort* wk  = (ushort*)alloc(WTE * 2);
    ushort* wv  = (ushort*)alloc(WTE * 2);
    ushort* w0  = (ushort*)alloc(WTE * 2);
    ushort* wr  = (ushort*)alloc(WTE * 2);
    ushort* wf0 = (ushort*)alloc(WTE * 2);
    ushort* wf1 = (ushort*)alloc(WTE * 2);
    float* stats = (float*)alloc(8 * 64 * sizeof(float));   // 2 LN inst/layer
    float* csr   = (float*)alloc(WTE / D_MODEL * sizeof(float)); // colsum(Wr): 4096

    const int CVT_BLOCKS = (int)(WTE / (256 * 8));             // 2048
    const dim3 GEMM_GRID(NTOK / 128, D_MODEL / 128);           // (64, 8)
    const dim3 QKV_GRID(NTOK / 128, 3 * D_MODEL / 128);        // (64, 24)
    const dim3 FLASH_GRID(BATCH * HEADS, SEQ / 128);           // (128, 8)

    cvt_f32_bf16<<<CVT_BLOCKS, 256, 0, stream>>>(Wq,   wq);
    cvt_f32_bf16<<<CVT_BLOCKS, 256, 0, stream>>>(Wk,   wk);
    cvt_f32_bf16<<<CVT_BLOCKS, 256, 0, stream>>>(Wv,   wv);
    cvt_f32_bf16<<<CVT_BLOCKS, 256, 0, stream>>>(W0,   w0);
    cvt_f32_bf16<<<CVT_BLOCKS, 256, 0, stream>>>(Wr_w, wr);
    cvt_f32_bf16<<<CVT_BLOCKS, 256, 0, stream>>>(Wf0w, wf0);
    cvt_f32_bf16<<<CVT_BLOCKS, 256, 0, stream>>>(Wf1w, wf1);
    colsum_k<<<LAYERS * D_MODEL / 4, 256, 0, stream>>>(wr, csr);
    zero_stats512<<<1, 256, 0, stream>>>(stats);

    add_pos<<<(NTOK * D_MODEL) / 256, 256, 0, stream>>>(X, x);

    for (int l = 0; l < LAYERS; l++) {
        const size_t WO = (size_t)l * D_MODEL * D_MODEL;
        const ushort* Wq_l  = wq  + WO;
        const ushort* Wk_l  = wk  + WO;
        const ushort* Wv_l  = wv  + WO;
        const ushort* W0_l  = w0  + WO;
        const ushort* Wr_l  = wr  + WO;
        const ushort* W0w_l = wf0 + WO;
        const ushort* W1w_l = wf1 + WO;
        const float* Wrb_l = Wr_b + (size_t)l * D_MODEL;
        const float* W0b_l = Wf0b + (size_t)l * D_MODEL;
        const float* W1b_l = Wf1b + (size_t)l * D_MODEL;
        const float* cs_l  = csr + (size_t)l * D_MODEL;
        float* st0 = stats + (size_t)(2 * l) * 64;
        float* st1 = stats + (size_t)(2 * l + 1) * 64;

        // Q,K,V projections (fused; Q pre-scaled by 1/8)
        gemm_qkv<<<QKV_GRID, 256, 0, stream>>>(x, Wq_l, Wk_l, Wv_l, bQ, bK, bV);

        flash_attn<<<FLASH_GRID, 256, 0, stream>>>(bQ, bK, bV, bO);

        // s1 = x + O@W0^T -> bK (bf16) + LN stats (inst 2l)
        gemm_bt128<<<GEMM_GRID, 256, 0, stream>>>(bO, W0_l, nullptr, bK,
            x, st0, nullptr, 0, nullptr, nullptr);
        // r0 = LN(s1) @ Wr^T + br -> bV   (algebraic LN via st0 + colsum)
        gemm_bt128<<<GEMM_GRID, 256, 0, stream>>>(bK, Wr_l, Wrb_l, bV,
            nullptr, nullptr, nullptr, 0, st0, cs_l);
        // h0 = relu(r0 @ Wf0^T + b0) -> bQ
        gemm_bt128<<<GEMM_GRID, 256, 0, stream>>>(bV, W0w_l, W0b_l, bQ,
            nullptr, nullptr, nullptr, 1, nullptr, nullptr);
        // s2 = r0 + h0 @ Wf1^T + b1 -> bO + LN stats (inst 2l+1)
        gemm_bt128<<<GEMM_GRID, 256, 0, stream>>>(bQ, W1w_l, W1b_l, bO,
            bV, st1, nullptr, 0, nullptr, nullptr);
        // x = LN(s2) @ Wr^T + br -> x (last layer: fp32 straight to d_out)
        gemm_bt128<<<GEMM_GRID, 256, 0, stream>>>(bO, Wr_l, Wrb_l, x,
            nullptr, nullptr, (l == LAYERS - 1) ? out : nullptr, 0, st1, cs_l);
    }
}